// Round 13
// baseline (4378.395 us; speedup 1.0000x reference)
//
#include <hip/hip_runtime.h>
#include <hip/hip_bf16.h>

#define Tz 512
#define Hz 512
#define NG 8                    // batch groups
#define BG 16                   // batches per group
#define SL 16                   // h-columns per slice
#define NWAVE 6
#define NTHR (NWAVE * 64)
#define SIXH (6 * Hz)
#define HB_U32 (BG * Hz)        // per (parity,group): 16x512 tagged u32 = 32 KB
#define WS_U32 (2 * NG * HB_U32)    // exchange buffer: 512 KB

typedef __bf16 bf16x8 __attribute__((ext_vector_type(8)));
typedef float f32x4 __attribute__((ext_vector_type(4)));
typedef unsigned int u32;
typedef u32 u32x4v __attribute__((ext_vector_type(4)));

// Device-scope (MALL) tagged access. R7 lesson: cross-CU exchange must use
// sc0 sc1 — sc0-only "L2-local" never propagates to consumers on this part.
__device__ __forceinline__ u32x4v ld_coh_x4(const u32* p) {
  u32x4v r;
  asm volatile("global_load_dwordx4 %0, %1, off sc0 sc1" : "=v"(r) : "v"(p) : "memory");
  return r;
}
__device__ __forceinline__ void st_coh_u32(u32* p, u32 v) {
  asm volatile("global_store_dword %0, %1, off sc0 sc1" :: "v"(p), "v"(v) : "memory");
}
__device__ __forceinline__ void vm_wait0() {
  asm volatile("s_waitcnt vmcnt(0)" ::: "memory");
  __builtin_amdgcn_sched_barrier(0);
}
// Raw LDS-only barrier (orders hs/xs/gs staging without draining VMEM).
__device__ __forceinline__ void bar_lds() {
  asm volatile("s_waitcnt lgkmcnt(0)" ::: "memory");
  __builtin_amdgcn_s_barrier();
  __builtin_amdgcn_sched_barrier(0);
}
__device__ __forceinline__ float sigf(float x) { return 1.f / (1.f + __expf(-x)); }
__device__ __forceinline__ float tanh_f(float x) { return 2.f / (1.f + __expf(-2.f * x)) - 1.f; }
__device__ __forceinline__ u32 pk_bf16(float a, float b) {
  unsigned short lo = __builtin_bit_cast(unsigned short, (__bf16)a);
  unsigned short hi = __builtin_bit_cast(unsigned short, (__bf16)b);
  return (u32)lo | ((u32)hi << 16);
}

// Sentinel tags (0xFFFF != any t in [0,512)).
__global__ void lstm_init(u32* ws) {
  int i = blockIdx.x * blockDim.x + threadIdx.x;   // WS_U32 threads
  ws[i] = 0xFFFF0000u;
}

__global__ __launch_bounds__(NTHR) void lstm_main(
    const float* __restrict__ x, const int* __restrict__ lens,
    const float* __restrict__ Wg, const float* __restrict__ bg,
    float* __restrict__ out, u32* __restrict__ hb)
{
  const int tid = threadIdx.x;
  const int l   = tid & 63;
  const int w   = tid >> 6;          // wave id = gate chunk (0..4 gates, 5 = px5)
  const int wg  = blockIdx.x;        // 128 blocks
  const int pr  = wg & 3;            // group pair
  const int si  = wg >> 2;           // column slice 0..31
  const int giA = 2 * pr, giB = 2 * pr + 1;
  const int oct = l >> 4;
  const int lm  = l & 15;

  __shared__ __align__(16) char xs[2][2][BG * Hz * 2];   // [group][parity] 16 KB
  __shared__ __align__(16) char hs[2][BG * Hz * 2];      // [group] 16 KB
  __shared__ float gs[2][NWAVE][BG][SL];                 // [group] gates

  // ---- resident W fragments: SHARED by both groups (same columns) ----
  const int colg = w * Hz + si * SL + lm;
  bf16x8 wf[16];
#pragma unroll
  for (int s = 0; s < 16; ++s)
#pragma unroll
    for (int j = 0; j < 8; ++j)
      wf[s][j] = (__bf16)Wg[(size_t)(32 * s + 8 * oct + j) * SIXH + colg];
  const float bv = bg[colg];
  const float bias = (w < 5) ? 2.f * bv : bv;   // ref adds b_in in BOTH projections

  const int erow = tid >> 4;
  const int ecol = tid & 15;
  float ccA = 0.f, ccB = 0.f;
  int lenA = 0, lenB = 0;
  if (tid < 256) { lenA = lens[giA * BG + erow]; lenB = lens[giB * BG + erow]; }

  float4 fA[8], fB[8];   // x(t+1) payloads (plain loads; compiler inserts waits)
  u32x4v hv4[8];         // tagged h chunk, time-shared A then B within an iter

  auto stage_x = [&](int G, const float4* fx, int par) {
#pragma unroll
    for (int Q = 0; Q < 4; ++Q) {
      u32x4v v = { pk_bf16(fx[2*Q].x, fx[2*Q].y),   pk_bf16(fx[2*Q].z, fx[2*Q].w),
                   pk_bf16(fx[2*Q+1].x, fx[2*Q+1].y), pk_bf16(fx[2*Q+1].z, fx[2*Q+1].w) };
      int byte = (erow * 1024 + ecol * 64 + 16 * Q) ^ ((erow & 7) << 4);
      *(u32x4v*)(&xs[G][par][byte]) = v;
    }
  };
  auto xmfma = [&](const char* xb, f32x4& a0, f32x4& a1) {
#pragma unroll
    for (int s = 0; s < 16; ++s) {
      int byte = (lm * 1024 + 64 * s + 16 * oct) ^ ((lm & 7) << 4);
      bf16x8 a = *(const bf16x8*)(xb + byte);
      if (s & 1) a1 = __builtin_amdgcn_mfma_f32_16x16x32_bf16(a, wf[s], a1, 0, 0, 0);
      else       a0 = __builtin_amdgcn_mfma_f32_16x16x32_bf16(a, wf[s], a0, 0, 0, 0);
    }
  };
  auto validate_stage = [&](int G, const u32* hp, u32 etag) {
    u32 badmask = 0;
#pragma unroll
    for (int q = 0; q < 8; ++q) {
      bool b = false;
#pragma unroll
      for (int j = 0; j < 4; ++j) b |= ((hv4[q][j] >> 16) != etag);
      badmask |= (u32)b << q;
    }
    int guard = 0;
    while (__builtin_expect(badmask != 0, 0)) {   // straggler peers only
#pragma unroll
      for (int q = 0; q < 8; ++q)
        if (badmask & (1u << q)) hv4[q] = ld_coh_x4(hp + 4 * q);
      vm_wait0();
      u32 nb = 0;
#pragma unroll
      for (int q = 0; q < 8; ++q) {
        bool b = false;
#pragma unroll
        for (int j = 0; j < 4; ++j) b |= ((hv4[q][j] >> 16) != etag);
        nb |= (u32)b << q;
      }
      badmask = nb;
      if (++guard > 1000000) break;               // finite on catastrophe only
    }
#pragma unroll
    for (int k2 = 0; k2 < 4; ++k2) {
      u32x4v o;
#pragma unroll
      for (int m = 0; m < 4; ++m) {
        int c = 8 * k2 + 2 * m;
        o[m] = __builtin_amdgcn_perm(hv4[(c + 1) >> 2][(c + 1) & 3],
                                     hv4[c >> 2][c & 3], 0x05040100u);
      }
      int byte = (erow * 1024 + ecol * 64 + 16 * k2) ^ ((erow & 7) << 4);
      *(u32x4v*)(&hs[G][byte]) = o;
    }
  };
  auto hmfma = [&](int G, f32x4& a0, f32x4& a1) {
#pragma unroll
    for (int s = 0; s < 16; ++s) {
      int byte = (lm * 1024 + 64 * s + 16 * oct) ^ ((lm & 7) << 4);
      bf16x8 a = *(const bf16x8*)(hs[G] + byte);
      if (s & 1) a1 = __builtin_amdgcn_mfma_f32_16x16x32_bf16(a, wf[s], a1, 0, 0, 0);
      else       a0 = __builtin_amdgcn_mfma_f32_16x16x32_bf16(a, wf[s], a0, 0, 0, 0);
    }
  };
  auto do_cell = [&](int G, int gi, float& cc, int len, int t) {
    float g0 = gs[G][0][erow][ecol], g1 = gs[G][1][erow][ecol], g2 = gs[G][2][erow][ecol];
    float g3 = gs[G][3][erow][ecol], g4 = gs[G][4][erow][ecol], px5 = gs[G][5][erow][ecol];
    float ig = sigf(g0), fg = sigf(g1), mg = tanh_f(g2), og = sigf(g3), hg = sigf(g4);
    float cn = ig * mg + fg * cc;
    float ot = og * tanh_f(cn);
    ot = hg * ot + (1.f - hg) * px5;
    bool act = t < len;
    float hvv = act ? ot : 0.f;
    cc = act ? cn : 0.f;
    u32 tagged = ((u32)t << 16) | (u32)__builtin_bit_cast(unsigned short, (__bf16)hvv);
    st_coh_u32(hb + ((size_t)(t & 1) * NG + gi) * HB_U32 + erow * Hz + si * SL + ecol, tagged);
    out[((size_t)(gi * BG + erow) * Tz + t) * Hz + si * SL + ecol] = hvv;
  };

  // ---- prologue: stage x(0) both groups; preload x(1) payloads ----
  if (tid < 256) {
    const float4* xa = (const float4*)(x + ((size_t)(giA * BG + erow) * Tz + 0) * Hz + ecol * 32);
    const float4* xb2 = (const float4*)(x + ((size_t)(giB * BG + erow) * Tz + 0) * Hz + ecol * 32);
    float4 t0[8], t1[8];
#pragma unroll
    for (int q = 0; q < 8; ++q) { t0[q] = xa[q]; t1[q] = xb2[q]; }
    stage_x(0, t0, 0); stage_x(1, t1, 0);
    const float4* ya = (const float4*)(x + ((size_t)(giA * BG + erow) * Tz + 1) * Hz + ecol * 32);
    const float4* yb = (const float4*)(x + ((size_t)(giB * BG + erow) * Tz + 1) * Hz + ecol * 32);
#pragma unroll
    for (int q = 0; q < 8; ++q) { fA[q] = ya[q]; fB[q] = yb[q]; }
  }
  __syncthreads();

  for (int t = 0; t < Tz; ++t) {
    const int parW = t & 1, parR = (t + 1) & 1;
    const bool do_h = (t > 0) && (tid < 256);
    const u32* hpA = hb + ((size_t)parR * NG + giA) * HB_U32 + erow * Hz + ecol * 32;
    const u32* hpB = hb + ((size_t)parR * NG + giB) * HB_U32 + erow * Hz + ecol * 32;

    // [1] stage xA(t+1)  (delays readA sample a bit more past A's publish)
    if (tid < 256 && t + 1 < Tz) stage_x(0, fA, parR);
    // [2] issue readA — A published mid-PREVIOUS iter (~1.5us ago: visible)
    if (do_h) {
#pragma unroll
      for (int q = 0; q < 8; ++q) hv4[q] = ld_coh_x4(hpA + 4 * q);
    }
    // [3] x-MFMA A while readA flies
    f32x4 aA0, aA1;
    aA0[0]=bias; aA0[1]=bias; aA0[2]=bias; aA0[3]=bias;
    aA1[0]=0.f; aA1[1]=0.f; aA1[2]=0.f; aA1[3]=0.f;
    xmfma(xs[0][parW], aA0, aA1);
    // [4] stage xB(t+1)  (more cover)
    if (tid < 256 && t + 1 < Tz) stage_x(1, fB, parR);
    // [5] drain; validate A; stage hs[0]
    if (tid < 256) vm_wait0();
    if (do_h) validate_stage(0, hpA, (u32)(t - 1));
    // [6] issue readB — B published at END of previous iter (~1.3us ago)
    if (do_h) {
#pragma unroll
      for (int q = 0; q < 8; ++q) hv4[q] = ld_coh_x4(hpB + 4 * q);
    }
    bar_lds();   // hs[0] + xs ready
    // [7] h-MFMA A; gates A
    if (w < 5 && t > 0) hmfma(0, aA0, aA1);
    { f32x4 g = aA0 + aA1;
#pragma unroll
      for (int r = 0; r < 4; ++r) gs[0][w][oct * 4 + r][lm] = g[r]; }
    bar_lds();   // gates A ready
    // [8] cell A: publish + out (stores float; covers readB flight)
    if (tid < 256) do_cell(0, giA, ccA, lenA, t);
    // [9] x-MFMA B (more readB cover)
    f32x4 aB0, aB1;
    aB0[0]=bias; aB0[1]=bias; aB0[2]=bias; aB0[3]=bias;
    aB1[0]=0.f; aB1[1]=0.f; aB1[2]=0.f; aB1[3]=0.f;
    xmfma(xs[1][parW], aB0, aB1);
    // [10] drain; validate B; stage hs[1]; issue x(t+2) loads (plain)
    if (tid < 256) vm_wait0();
    if (do_h) validate_stage(1, hpB, (u32)(t - 1));
    if (tid < 256 && t + 2 < Tz) {
      const float4* ya = (const float4*)(x + ((size_t)(giA * BG + erow) * Tz + (t + 2)) * Hz + ecol * 32);
      const float4* yb = (const float4*)(x + ((size_t)(giB * BG + erow) * Tz + (t + 2)) * Hz + ecol * 32);
#pragma unroll
      for (int q = 0; q < 8; ++q) { fA[q] = ya[q]; fB[q] = yb[q]; }
    }
    bar_lds();   // hs[1] ready
    // [11] h-MFMA B; gates B
    if (w < 5 && t > 0) hmfma(1, aB0, aB1);
    { f32x4 g = aB0 + aB1;
#pragma unroll
      for (int r = 0; r < 4; ++r) gs[1][w][oct * 4 + r][lm] = g[r]; }
    bar_lds();   // gates B ready
    // [12] cell B: publish + out
    if (tid < 256) do_cell(1, giB, ccB, lenB, t);
  }
}

extern "C" void kernel_launch(void* const* d_in, const int* in_sizes, int n_in,
                              void* d_out, int out_size, void* d_ws, size_t ws_size,
                              hipStream_t stream) {
  const float* x  = (const float*)d_in[0];
  const int* lens = (const int*)d_in[1];      // jax x64 disabled -> int32
  const float* Wg = (const float*)d_in[2];
  const float* bg = (const float*)d_in[3];
  float* out = (float*)d_out;                 // reference output dtype: float32
  u32* hb = (u32*)d_ws;                       // 512KB tagged h exchange

  hipLaunchKernelGGL(lstm_init, dim3(WS_U32 / 256), dim3(256), 0, stream, hb);
  // 128 blocks x 108KB LDS -> 1 block/CU; two phase-staggered groups per block
  hipLaunchKernelGGL(lstm_main, dim3(128), dim3(NTHR), 0, stream,
                     x, lens, Wg, bg, out, hb);
}